// Round 4
// baseline (190.864 us; speedup 1.0000x reference)
//
#include <hip/hip_runtime.h>
#include <hip/hip_bf16.h>

#define CRF_B 1024
#define CRF_T 512
#define CRF_C 32
#define DPF 8

typedef float f32x4 __attribute__((ext_vector_type(4)));
typedef short s16x8 __attribute__((ext_vector_type(8)));

// f32 -> bf16 bits, round-nearest-even (init path only)
static __device__ __forceinline__ unsigned f2bf(float f) {
    union { float f; unsigned u; } v; v.f = f;
    return (v.u + 0x7FFFu + ((v.u >> 16) & 1u)) >> 16;
}

#define CVT_PK(dst, lo, hi) \
    asm("v_cvt_pk_bf16_f32 %0, %1, %2" : "=v"(dst) : "v"(lo), "v"(hi))
#define SWAP32(a, b) \
    asm("v_permlane32_swap_b32 %0, %1" : "+v"(a), "+v"(b))
#define SWAP16(a, b) \
    asm("v_permlane16_swap_b32 %0, %1" : "+v"(a), "+v"(b))

// One wave = 16 batch rows. lane l: r = l&15 (batch col), h = l>>4 (0..3).
// State: P[k][r] = exp(alpha[k] - s) as bf16 in MFMA-B layout
//   (lane holds k = 8h..8h+7 of col r).
// Step: D[j][r] = sum_k E'[j][k] P[k][r] via 2x mfma_f32_16x16x32_bf16
//   (A0 = rows j=0..15 of E'=exp(trans), A1 = rows 16..31; static).
// D layout: lane holds col r, j = 4h+i (D0) and 16+4h+i (D1).
// Output: alpha_t[j] = x_t[j] + sU + log(D)   (sU = s_{t-1})
// New state: p' = D * exp(x + sU - sC)        (sC = s_t = alpha_{t-2}[0])
// Relayout D->B: pack bf16 pairs then 2x(permlane32_swap+permlane16_swap).
// Shift chain: sU <- sC; sC <- aQ; aQ <- shfl(alpha_t[0]) — 1 step of slack.
__global__ __launch_bounds__(64) void crf_fwd_kernel(
    const float* __restrict__ x,      // [B, T, C]
    const float* __restrict__ trans,  // [C, C]
    const float* __restrict__ orig,   // [C]
    float* __restrict__ out)          // [T, B, C]
{
    const int l = threadIdx.x;
    const int r = l & 15;
    const int h = l >> 4;
    const int b = blockIdx.x * 16 + r;

    // ---- static A fragments: E'[j][k] = exp(trans[j][k]) in bf16 ----
    s16x8 A0, A1;
    #pragma unroll
    for (int e = 0; e < 8; ++e) {
        int k = h * 8 + e;
        A0[e] = (short)f2bf(__expf(trans[r * CRF_C + k]));          // j = r
        A1[e] = (short)f2bf(__expf(trans[(16 + r) * CRF_C + k]));   // j = 16+r
    }

    const float* xb = x + (size_t)b * CRF_T * CRF_C;   // x[b][t][c]

    // ---- t = 0 init ----
    float s0 = xb[0] + orig[0];                        // alpha_0[0]

    // state (B-layout, k = 8h..8h+7)
    f32x4 ib0 = *(const f32x4*)(xb + 8 * h);
    f32x4 ib1 = *(const f32x4*)(xb + 8 * h + 4);
    f32x4 ob0 = *(const f32x4*)(orig + 8 * h);
    f32x4 ob1 = *(const f32x4*)(orig + 8 * h + 4);
    unsigned q0, q1, q2, q3;
    CVT_PK(q0, __expf(ib0[0] + ob0[0] - s0), __expf(ib0[1] + ob0[1] - s0));
    CVT_PK(q1, __expf(ib0[2] + ob0[2] - s0), __expf(ib0[3] + ob0[3] - s0));
    CVT_PK(q2, __expf(ib1[0] + ob1[0] - s0), __expf(ib1[1] + ob1[1] - s0));
    CVT_PK(q3, __expf(ib1[2] + ob1[2] - s0), __expf(ib1[3] + ob1[3] - s0));
    s16x8 Bf;
    {
        union { unsigned w[4]; s16x8 v; } bu;
        bu.w[0] = q0; bu.w[1] = q1; bu.w[2] = q2; bu.w[3] = q3;
        Bf = bu.v;
    }

    // t = 0 outputs (D-layout j positions)
    {
        f32x4 xd0 = *(const f32x4*)(xb + 4 * h);
        f32x4 xd1 = *(const f32x4*)(xb + 16 + 4 * h);
        f32x4 od0 = *(const f32x4*)(orig + 4 * h);
        f32x4 od1 = *(const f32x4*)(orig + 16 + 4 * h);
        f32x4 a00, a01;
        #pragma unroll
        for (int i = 0; i < 4; ++i) { a00[i] = xd0[i] + od0[i]; a01[i] = xd1[i] + od1[i]; }
        *(f32x4*)(out + (size_t)b * CRF_C + 4 * h) = a00;
        *(f32x4*)(out + (size_t)b * CRF_C + 16 + 4 * h) = a01;
    }

    // ---- emission prefetch (D-layout), depth DPF ----
    f32x4 plo[DPF], phi[DPF];
    #pragma unroll
    for (int d_ = 0; d_ < DPF; ++d_) {
        const float* pa = xb + (size_t)(1 + d_) * CRF_C;
        plo[d_] = *(const f32x4*)(pa + 4 * h);
        phi[d_] = *(const f32x4*)(pa + 16 + 4 * h);
    }

    const f32x4 zz = {0.f, 0.f, 0.f, 0.f};
    float sU = s0, sC = s0, aQ = s0;
    float* op0 = out + ((size_t)CRF_B + b) * CRF_C + 4 * h;   // t=1 row

#define STEP(T_, D_, REFILL_)                                                  \
    {                                                                          \
        f32x4 xl = plo[D_], xh = phi[D_];                                      \
        if (REFILL_) {                                                         \
            int tn = (T_) + DPF; if (tn > CRF_T - 1) tn = CRF_T - 1;           \
            const float* pa = xb + (size_t)tn * CRF_C;                         \
            plo[D_] = *(const f32x4*)(pa + 4 * h);                             \
            phi[D_] = *(const f32x4*)(pa + 16 + 4 * h);                        \
        }                                                                      \
        f32x4 D0 = __builtin_amdgcn_mfma_f32_16x16x32_bf16(A0, Bf, zz, 0, 0, 0); \
        f32x4 D1 = __builtin_amdgcn_mfma_f32_16x16x32_bf16(A1, Bf, zz, 0, 0, 0); \
        float dlt = sU - sC;                                                   \
        float f0 = __expf(xl[0] + dlt), f1 = __expf(xl[1] + dlt);              \
        float f2 = __expf(xl[2] + dlt), f3 = __expf(xl[3] + dlt);              \
        float g0 = __expf(xh[0] + dlt), g1 = __expf(xh[1] + dlt);              \
        float g2 = __expf(xh[2] + dlt), g3 = __expf(xh[3] + dlt);              \
        f32x4 alo, ahi;                                                        \
        alo[0] = xl[0] + sU + __logf(D0[0]);                                   \
        alo[1] = xl[1] + sU + __logf(D0[1]);                                   \
        alo[2] = xl[2] + sU + __logf(D0[2]);                                   \
        alo[3] = xl[3] + sU + __logf(D0[3]);                                   \
        ahi[0] = xh[0] + sU + __logf(D1[0]);                                   \
        ahi[1] = xh[1] + sU + __logf(D1[1]);                                   \
        ahi[2] = xh[2] + sU + __logf(D1[2]);                                   \
        ahi[3] = xh[3] + sU + __logf(D1[3]);                                   \
        *(f32x4*)op0 = alo;                                                    \
        *(f32x4*)(op0 + 16) = ahi;                                             \
        op0 += CRF_B * CRF_C;                                                  \
        float a0new = __shfl(alo[0], r, 64);                                   \
        unsigned w0, w1, w2, w3;                                               \
        CVT_PK(w0, D0[0] * f0, D0[1] * f1);                                    \
        CVT_PK(w1, D0[2] * f2, D0[3] * f3);                                    \
        CVT_PK(w2, D1[0] * g0, D1[1] * g1);                                    \
        CVT_PK(w3, D1[2] * g2, D1[3] * g3);                                    \
        SWAP32(w0, w2); SWAP16(w0, w2);                                        \
        SWAP32(w1, w3); SWAP16(w1, w3);                                        \
        {                                                                      \
            union { unsigned w[4]; s16x8 v; } bu_;                             \
            bu_.w[0] = w0; bu_.w[1] = w1; bu_.w[2] = w2; bu_.w[3] = w3;        \
            Bf = bu_.v;                                                        \
        }                                                                      \
        sU = sC; sC = aQ; aQ = a0new;                                          \
    }

    int t = 1;
    for (int tb = 0; tb < 63; ++tb) {          // t = 1 .. 504
        #pragma unroll
        for (int to = 0; to < 8; ++to) {
            STEP(t, to, 1);
            ++t;
        }
    }
    #pragma unroll
    for (int to = 0; to < 7; ++to) {           // t = 505 .. 511
        STEP(t, to, 0);
        ++t;
    }
#undef STEP
}

extern "C" void kernel_launch(void* const* d_in, const int* in_sizes, int n_in,
                              void* d_out, int out_size, void* d_ws, size_t ws_size,
                              hipStream_t stream) {
    const float* pad_x = (const float*)d_in[0];
    const float* trans = (const float*)d_in[1];
    const float* orig  = (const float*)d_in[2];
    float* out = (float*)d_out;

    crf_fwd_kernel<<<dim3(CRF_B / 16), dim3(64), 0, stream>>>(pad_x, trans, orig, out);
}